// Round 1
// baseline (2378.876 us; speedup 1.0000x reference)
//
#include <hip/hip_runtime.h>
#include <cstdint>
#include <cstddef>

// GRU last-hidden: B=1024, T=512, I=H=256.
// Phase 1 (k_proj): xi = x @ W_ih^T + b_ih  -> bf16 in workspace (chunked over T).
// Phase 2 (k_rec): persistent recurrence, 256 blocks x 4 batch rows, W_hh bf16
//                  resident in VGPRs (48 frags/wave), 1 barrier per step.
// Workspace auto-chunking over T handles unknown ws_size.

#define BB 1024
#define TT 512
#define II 256
#define HH 256
#define G3 768   // 3*H

using bfrag = __attribute__((ext_vector_type(8))) short;   // 8 bf16 = 4 VGPRs (guide §3)
using f32x4 = __attribute__((ext_vector_type(4))) float;   // MFMA C/D

static __device__ __forceinline__ unsigned short f2b(float f){
  unsigned u = __builtin_bit_cast(unsigned, f);
  u += 0x7FFFu + ((u >> 16) & 1u);          // RNE; inputs are finite
  return (unsigned short)(u >> 16);
}
static __device__ __forceinline__ float b2f(unsigned short s){
  unsigned u = ((unsigned)s) << 16;
  return __builtin_bit_cast(float, u);
}
static __device__ __forceinline__ float sigm(float x){
  float e = __builtin_amdgcn_exp2f(-1.4426950408889634f * x);
  return __builtin_amdgcn_rcpf(1.0f + e);
}
static __device__ __forceinline__ float tanh_(float x){
  float e = __builtin_amdgcn_exp2f(2.8853900817779268f * x);   // exp(2x)
  return (e - 1.0f) * __builtin_amdgcn_rcpf(e + 1.0f);
}

// ---------------------------------------------------------------------------
// k_init: convert W_ih / W_hh (fp32 [768][256]) to frag-major bf16:
//   out[((nt*8+ks)*64 + L)*8 + j] = W[nt*16 + (L&15)][ks*32 + (L>>4)*8 + j]
// so both GEMM kernels load B-frags as flat coalesced 16B/lane.
// Also zeroes persistent h and d_out (rows with seq_len==0 must stay 0).
// ---------------------------------------------------------------------------
__global__ void k_init(const float* __restrict__ Wih, const float* __restrict__ Whh,
                       unsigned short* __restrict__ Wihb, unsigned short* __restrict__ Whhb,
                       float* __restrict__ hws, float* __restrict__ out)
{
  int tid = blockIdx.x*256 + threadIdx.x;      // grid 1024*256 = 262144
  if (tid < 48*8*64*8){                        // 196608 weights per matrix
    int j  = tid & 7;
    int L  = (tid >> 3) & 63;
    int ks = (tid >> 9) & 7;
    int nt = tid >> 12;
    int src = (nt*16 + (L&15))*II + ks*32 + (L>>4)*8 + j;
    Wihb[tid] = f2b(Wih[src]);
    Whhb[tid] = f2b(Whh[src]);
  }
  if (tid < BB*HH){ hws[tid] = 0.0f; out[tid] = 0.0f; }
}

// ---------------------------------------------------------------------------
// k_proj: 256 threads = 4 waves; each wave 4 m-tiles (64 rows), block 256 rows.
// A-frags direct from global fp32 (16 rows x 128B contiguous per (mt,ks) -> no
// overfetch), W chunk (64 cols) staged frag-major into LDS, shared by 4 waves.
// Rows are flat (b*Tc + t_local) within the chunk; m-tiles never cross b
// because Tc % 16 == 0.
// ---------------------------------------------------------------------------
__global__ __launch_bounds__(256, 2) void k_proj(
    const float* __restrict__ x, const unsigned short* __restrict__ Wihb,
    const float* __restrict__ bih, unsigned short* __restrict__ xi,
    int t0, int Tc)
{
  __shared__ __align__(16) uint4 wsd[2048];    // 32KB: 4 n-tiles x 8 ks x 64 lanes
  const int tid = threadIdx.x, wv = tid>>6, L = tid&63;
  const int lr = L & 15, q = L >> 4;
  const int tpb = Tc >> 4;                     // m-tiles per batch row in chunk
  const int tile0 = blockIdx.x*16 + wv*4;

  bfrag a[4][8];
  int bs[4], tls[4];
#pragma unroll
  for (int m=0;m<4;++m){
    int tile = tile0 + m;
    int b = tile / tpb;
    int tl = (tile - b*tpb)*16;
    bs[m]=b; tls[m]=tl;
    const float* xr = x + ((size_t)b*TT + t0 + tl + lr)*II;
#pragma unroll
    for (int ks=0;ks<8;++ks){
      float4 v0 = *(const float4*)(xr + ks*32 + q*8);
      float4 v1 = *(const float4*)(xr + ks*32 + q*8 + 4);
      bfrag f;
      f[0]=(short)f2b(v0.x); f[1]=(short)f2b(v0.y); f[2]=(short)f2b(v0.z); f[3]=(short)f2b(v0.w);
      f[4]=(short)f2b(v1.x); f[5]=(short)f2b(v1.y); f[6]=(short)f2b(v1.z); f[7]=(short)f2b(v1.w);
      a[m][ks]=f;
    }
  }
  for (int nc=0; nc<12; ++nc){
    __syncthreads();                            // protect wsd reuse
    const uint4* wg = (const uint4*)Wihb + nc*2048;
#pragma unroll
    for (int it=0; it<8; ++it) wsd[it*256+tid] = wg[it*256+tid];
    __syncthreads();
    f32x4 acc[4][4];
#pragma unroll
    for (int nt=0;nt<4;++nt){
      float bv = bih[nc*64 + nt*16 + lr];       // bias folded into C
#pragma unroll
      for (int m=0;m<4;++m) acc[m][nt] = (f32x4){bv,bv,bv,bv};
    }
#pragma unroll
    for (int ks=0;ks<8;++ks){
#pragma unroll
      for (int nt=0;nt<4;++nt){
        bfrag bf = ((const bfrag*)wsd)[(nt*8+ks)*64 + L];
#pragma unroll
        for (int m=0;m<4;++m)
          acc[m][nt] = __builtin_amdgcn_mfma_f32_16x16x32_bf16(a[m][ks], bf, acc[m][nt], 0,0,0);
      }
    }
    // C/D layout: col = lane&15, row = (lane>>4)*4 + reg  (guide §3, m89-verified)
#pragma unroll
    for (int m=0;m<4;++m){
      unsigned short* o = xi + ((size_t)(tls[m] + 4*q)*BB + bs[m])*G3 + nc*64 + lr;
#pragma unroll
      for (int nt=0;nt<4;++nt)
#pragma unroll
        for (int r=0;r<4;++r)
          o[(size_t)r*BB*G3 + nt*16] = f2b(acc[m][nt][r]);
    }
  }
}

// ---------------------------------------------------------------------------
// k_rec: 256 blocks x 512 threads (8 waves). Block owns 4 batch rows for the
// whole chunk. Wave w owns gh columns {32w..32w+31} in all 3 gates: resident
// W frags Wf[6][8] = 192 VGPRs/lane. A-frag broadcast: row = lane&3 (only 4
// real rows), stride 288 shorts to keep 16B align + benign 2-way banks.
// One __syncthreads per step (h and xi LDS double-buffered).
// Gates run on lanes q==0 (acc rows 0-3 live in regs 0-3 there) — known 4x
// lane waste, round-2 target.
// ---------------------------------------------------------------------------
__global__ __launch_bounds__(512, 2) void k_rec(
    const unsigned short* __restrict__ xi,    // [Tc][1024][768] bf16 (chunk-local)
    const unsigned short* __restrict__ Whhb,  // frag-major bf16
    const float* __restrict__ bhh,
    const int* __restrict__ seq,
    float* __restrict__ hws,                  // [1024][256] f32 persistent h
    float* __restrict__ out,                  // [1024][256] f32 hn
    int t0, int Tc)
{
  __shared__ __align__(16) unsigned short hsh[2][4*288];   // 4.5KB
  __shared__ __align__(16) unsigned short xish[2][4*768];  // 12KB
  const int tid = threadIdx.x;
  const int wv = tid >> 6;
  const int L  = tid & 63;
  const int lr = L & 15;
  const int q  = L >> 4;
  const int b0 = blockIdx.x * 4;

  // resident W_hh fragments + per-column bias (folded into MFMA C)
  bfrag Wf[6][8];
  float bias[6];
#pragma unroll
  for (int g = 0; g < 3; ++g)
#pragma unroll
    for (int p = 0; p < 2; ++p){
      const int f  = g*2 + p;
      const int nt = g*16 + 2*wv + p;
#pragma unroll
      for (int ks = 0; ks < 8; ++ks)
        Wf[f][ks] = ((const bfrag*)Whhb)[(nt*8 + ks)*64 + L];
      bias[f] = bhh[g*256 + 32*wv + 16*p + lr];
    }

  const int c0 = 32*wv + lr, c1 = c0 + 16;
  float hp[8];       // fp32 h for (rows 0..3) x (c0,c1), lanes q==0 only
  int slr[4];        // chunk-local step at which hn := h_new (t == seq_len-1)
  if (q == 0){
#pragma unroll
    for (int r = 0; r < 4; ++r){
      hp[2*r+0] = hws[(b0+r)*HH + c0];
      hp[2*r+1] = hws[(b0+r)*HH + c1];
      slr[r] = seq[b0+r] - t0 - 1;
      hsh[0][r*288 + c0] = f2b(hp[2*r+0]);
      hsh[0][r*288 + c1] = f2b(hp[2*r+1]);
    }
  }
  const bool stager = (tid < 384);             // waves 0..5 stage 6KB xi/step
  const uint4* xg = (const uint4*)xi;
  if (stager){
    uint4 v = xg[(size_t)b0*96 + tid];
    *((uint4*)xish[0] + tid) = v;
  }
  __syncthreads();

  for (int tl = 0; tl < Tc; ++tl){
    const int cur = tl & 1;
    // issue prefetch of xi(t+1) early: latency hides under MFMA+gates
    uint4 xv;
    if (stager){
      int tn = (tl+1 < Tc) ? tl+1 : Tc-1;
      xv = xg[((size_t)tn*BB + b0)*96 + tid];
    }
    // --- GEMM: gh = h @ W_hh^T + b_hh ---
    f32x4 acc[6];
#pragma unroll
    for (int f = 0; f < 6; ++f) acc[f] = (f32x4){bias[f],bias[f],bias[f],bias[f]};
#pragma unroll
    for (int ks = 0; ks < 8; ++ks){
      bfrag a = *(const bfrag*)&hsh[cur][(L&3)*288 + ks*32 + q*8];
#pragma unroll
      for (int f = 0; f < 6; ++f)
        acc[f] = __builtin_amdgcn_mfma_f32_16x16x32_bf16(a, Wf[f][ks], acc[f], 0, 0, 0);
    }
    // --- gates (lanes q==0; rows 0..3 are acc regs 0..3) ---
    if (q == 0){
#pragma unroll
      for (int r = 0; r < 4; ++r){
        const unsigned short* xrow = &xish[cur][r*G3];
        float xr0 = b2f(xrow[c0]),       xr1 = b2f(xrow[c1]);
        float xz0 = b2f(xrow[256 + c0]), xz1 = b2f(xrow[256 + c1]);
        float xn0 = b2f(xrow[512 + c0]), xn1 = b2f(xrow[512 + c1]);
        float rr0 = sigm(xr0 + acc[0][r]);
        float rr1 = sigm(xr1 + acc[1][r]);
        float zz0 = sigm(xz0 + acc[2][r]);
        float zz1 = sigm(xz1 + acc[3][r]);
        float nn0 = tanh_(xn0 + rr0*acc[4][r]);
        float nn1 = tanh_(xn1 + rr1*acc[5][r]);
        float h0 = nn0 + zz0*(hp[2*r+0] - nn0);   // (1-z)n + z*h
        float h1 = nn1 + zz1*(hp[2*r+1] - nn1);
        hp[2*r+0] = h0; hp[2*r+1] = h1;
        hsh[cur^1][r*288 + c0] = f2b(h0);
        hsh[cur^1][r*288 + c1] = f2b(h1);
        if (tl == slr[r]){                        // last step with t+1<=seq_len
          out[(b0+r)*HH + c0] = h0;
          out[(b0+r)*HH + c1] = h1;
        }
      }
    }
    if (stager) *((uint4*)xish[cur^1] + tid) = xv;
    __syncthreads();
  }
  if (q == 0){
#pragma unroll
    for (int r = 0; r < 4; ++r){
      hws[(b0+r)*HH + c0] = hp[2*r+0];
      hws[(b0+r)*HH + c1] = hp[2*r+1];
    }
  }
}

// ---------------------------------------------------------------------------
// ws layout: [0, 384K) W_hh frag-bf16 | [384K, 768K) W_ih frag-bf16
//            [1M, 2M) persistent h fp32 | [3M, ...) xi chunk bf16
// Tc auto-halved until the chunk fits ws (needs >= ~27MB at Tc=16).
// ---------------------------------------------------------------------------
extern "C" void kernel_launch(void* const* d_in, const int* in_sizes, int n_in,
                              void* d_out, int out_size, void* d_ws, size_t ws_size,
                              hipStream_t stream)
{
  (void)in_sizes; (void)n_in; (void)out_size;
  const float* x   = (const float*)d_in[0];
  const int*   seq = (const int*)  d_in[1];
  const float* Wih = (const float*)d_in[2];
  const float* Whh = (const float*)d_in[3];
  const float* bih = (const float*)d_in[4];
  const float* bhh = (const float*)d_in[5];
  float* out = (float*)d_out;
  char* ws = (char*)d_ws;
  unsigned short* Whhb = (unsigned short*)(ws);
  unsigned short* Wihb = (unsigned short*)(ws + 393216);
  float* hws = (float*)(ws + (1u<<20));
  unsigned short* xiw = (unsigned short*)(ws + 3u*(1u<<20));
  size_t avail = (ws_size > (size_t)(3u<<20)) ? ws_size - (size_t)(3u<<20) : 0;
  int Tc = TT;
  while (Tc > 16 && (size_t)Tc*BB*G3*2 > avail) Tc >>= 1;

  k_init<<<dim3(1024), dim3(256), 0, stream>>>(Wih, Whh, Wihb, Whhb, hws, out);
  for (int t0 = 0; t0 < TT; t0 += Tc){
    k_proj<<<dim3((BB/256)*Tc), dim3(256), 0, stream>>>(x, Wihb, bih, xiw, t0, Tc);
    k_rec <<<dim3(256), dim3(512), 0, stream>>>(xiw, Whhb, bhh, seq, hws, out, t0, Tc);
  }
}